// Round 3
// baseline (179.755 us; speedup 1.0000x reference)
//
#include <hip/hip_runtime.h>
#include <math.h>

#define B_ 32
#define H_ 112
#define W_ 112
#define C_ 192
#define C4 (C_/4)            // 48
#define R_ 8                 // output rows per block
#define TILES (H_/R_)        // 14 tiles per image
#define HALO 3
#define SR (R_ + 2*HALO)     // 14 staged (avg,max) rows
#define SW (W_ + 2*HALO)     // 118 staged cols
#define NT_ 512              // threads per block (8 waves)

typedef float nf4 __attribute__((ext_vector_type(4)));

// One block per (b, 8-row tile). Three phases:
//  1) channel avg/max for the 14-row halo window -> LDS (regular loads: allocate in L3)
//  2) 7x7 conv + sigmoid entirely in LDS (global ws2/att buffers eliminated)
//  3) re-read own 8 rows of x (short reuse distance -> L3 hit) * att, NT store
__global__ __launch_bounds__(512) void fused_kernel(const float* __restrict__ x,
                                                    const float* __restrict__ w,
                                                    float* __restrict__ out) {
    __shared__ float2 sm[SR][SW];     // (avg,max), zero-padded halo: 13.2 KB
    __shared__ float  sw[98];
    __shared__ float  satt[R_ * W_];  // 3.6 KB

    const int tid = threadIdx.x;
    const int b   = blockIdx.x / TILES;
    const int t   = blockIdx.x - b * TILES;
    const int y0  = t * R_;

    if (tid < 98) sw[tid] = w[tid];
    for (int i = tid; i < SR * SW; i += NT_)
        ((float2*)sm)[i] = make_float2(0.0f, 0.0f);
    __syncthreads();

    // ---- phase 1: channel mean/max, 16 lanes per position, 3 float4/lane ----
    const int lane  = tid & 63;
    const int sub   = lane & 15;
    const int pbase = (tid >> 6) * 4 + (lane >> 4);   // 0..31, uniform per 16-lane group
    for (int r = 0; r < SR; ++r) {
        const int yy = y0 + r - HALO;
        if (yy < 0 || yy >= H_) continue;             // halo row outside image stays zero
        const float* xrow = x + (size_t)(b * H_ + yy) * W_ * C_;
        #pragma unroll
        for (int i = 0; i < 4; ++i) {
            const int pos = i * 32 + pbase;           // 112 positions in 3.5 passes
            if (pos < W_) {
                const float4* xp = (const float4*)(xrow + (size_t)pos * C_);
                float4 v0 = xp[sub];
                float4 v1 = xp[sub + 16];
                float4 v2 = xp[sub + 32];
                float s = (v0.x + v0.y + v0.z + v0.w)
                        + (v1.x + v1.y + v1.z + v1.w)
                        + (v2.x + v2.y + v2.z + v2.w);
                float m0 = fmaxf(fmaxf(v0.x, v0.y), fmaxf(v0.z, v0.w));
                float m1 = fmaxf(fmaxf(v1.x, v1.y), fmaxf(v1.z, v1.w));
                float m2 = fmaxf(fmaxf(v2.x, v2.y), fmaxf(v2.z, v2.w));
                float m  = fmaxf(m0, fmaxf(m1, m2));
                #pragma unroll
                for (int off = 8; off > 0; off >>= 1) {
                    s += __shfl_xor(s, off);
                    m = fmaxf(m, __shfl_xor(m, off));
                }
                if (sub == 0)
                    sm[r][HALO + pos] = make_float2(s * (1.0f / (float)C_), m);
            }
        }
    }
    __syncthreads();

    // ---- phase 2: 7x7 conv + sigmoid, bounds-check-free (halo pre-zeroed) ----
    for (int idx = tid; idx < R_ * W_; idx += NT_) {
        const int rr  = idx / W_;
        const int col = idx - rr * W_;
        float acc = 0.0f;
        #pragma unroll
        for (int ky = 0; ky < 7; ++ky) {
            #pragma unroll
            for (int kx = 0; kx < 7; ++kx) {
                float2 am = sm[rr + ky][col + kx];
                acc = fmaf(am.x, sw[(ky * 7 + kx) * 2 + 0], acc);
                acc = fmaf(am.y, sw[(ky * 7 + kx) * 2 + 1], acc);
            }
        }
        satt[idx] = 1.0f / (1.0f + __expf(-acc));
    }
    __syncthreads();

    // ---- phase 3: out = x * att over the tile's 8 rows ----
    // 8*112*48 = 43008 float4 = 84 exact iterations of 512 threads
    const size_t base4 = (size_t)(b * H_ + y0) * W_ * C4;
    const nf4* xr   = (const nf4*)x + base4;
    nf4*       orow = (nf4*)out + base4;
    #pragma unroll 4
    for (int k = 0; k < (R_ * W_ * C4) / NT_; ++k) {
        const int f4 = tid + k * NT_;
        nf4 v = xr[f4];                       // regular load: want the L3 hit
        v = v * satt[f4 / C4];
        __builtin_nontemporal_store(v, &orow[f4]);  // dead data: don't pollute L3
    }
}

extern "C" void kernel_launch(void* const* d_in, const int* in_sizes, int n_in,
                              void* d_out, int out_size, void* d_ws, size_t ws_size,
                              hipStream_t stream) {
    const float* x = (const float*)d_in[0];
    const float* w = (const float*)d_in[1];
    float* out = (float*)d_out;
    fused_kernel<<<B_ * TILES, NT_, 0, stream>>>(x, w, out);
}

// Round 4
// 158.781 us; speedup vs baseline: 1.1321x; 1.1321x over previous
//
#include <hip/hip_runtime.h>
#include <math.h>

#define B_ 32
#define H_ 112
#define W_ 112
#define C_ 192
#define C4 (C_/4)              // 48
#define CHB 8                  // batches per chunk (77 MB of x -> fits L3 with margin)
#define NCHUNK (B_/CHB)        // 4
#define CPOS (CHB*H_*W_)       // 100352 positions per chunk
#define HALO 3

typedef float nf4 __attribute__((ext_vector_type(4)));

// ---------------- Reduce: per-position channel mean + max (chunked) --------
// 4 positions per wave, 16 lanes per position, 3 float4 per lane.
__global__ __launch_bounds__(256) void reduce_kernel(const float* __restrict__ x,
                                                     float2* __restrict__ ws2,
                                                     int p0) {
    const int wave = threadIdx.x >> 6;
    const int lane = threadIdx.x & 63;
    const int sub  = lane & 15;
    const int p = p0 + blockIdx.x * 16 + wave * 4 + (lane >> 4);  // grid exact: CPOS/16

    const float4* xp = (const float4*)(x + (size_t)p * C_);
    float4 v0 = xp[sub];
    float4 v1 = xp[sub + 16];
    float4 v2 = xp[sub + 32];
    float s = (v0.x + v0.y + v0.z + v0.w)
            + (v1.x + v1.y + v1.z + v1.w)
            + (v2.x + v2.y + v2.z + v2.w);
    float m0 = fmaxf(fmaxf(v0.x, v0.y), fmaxf(v0.z, v0.w));
    float m1 = fmaxf(fmaxf(v1.x, v1.y), fmaxf(v1.z, v1.w));
    float m2 = fmaxf(fmaxf(v2.x, v2.y), fmaxf(v2.z, v2.w));
    float m  = fmaxf(m0, fmaxf(m1, m2));
    #pragma unroll
    for (int off = 8; off > 0; off >>= 1) {
        s += __shfl_xor(s, off);
        m = fmaxf(m, __shfl_xor(m, off));
    }
    if (sub == 0) {
        float2 r;
        r.x = s * (1.0f / (float)C_);
        r.y = m;
        ws2[p] = r;
    }
}

// -------- ConvMul: 7x7 conv + sigmoid + multiply, one block per HALF-row ---
// Chunk c's x rows were just streamed by reduce_kernel -> reuse distance
// <= ~80 MB -> L3 hits. Regular x loads (want the hit), NT stores (dead data).
__global__ __launch_bounds__(256) void convmul_kernel(const float* __restrict__ x,
                                                      const float2* __restrict__ ws2,
                                                      const float* __restrict__ w,
                                                      float* __restrict__ out,
                                                      int row0) {
    __shared__ float2 sm[7][64];   // 62 used (56 cols + 6 halo), zero-padded
    __shared__ float  sw[98];
    __shared__ float  satt[56];

    const int tid  = threadIdx.x;
    const int rowg = row0 + ((int)blockIdx.x >> 1);   // global (b*H_+y) row
    const int x0   = ((int)blockIdx.x & 1) * 56;      // half-row start col
    const int b    = rowg / H_;
    const int y    = rowg - b * H_;

    if (tid < 98) sw[tid] = w[tid];

    // stage 7 rows x 62 cols of (avg,max), zero outside the image
    const float2* wsb = ws2 + (size_t)b * (H_ * W_);
    for (int i = tid; i < 7 * 62; i += 256) {
        const int r  = i / 62;
        const int c  = i - r * 62;
        const int yy = y + r - HALO;
        const int xx = x0 + c - HALO;
        float2 v = make_float2(0.0f, 0.0f);
        if (yy >= 0 && yy < H_ && xx >= 0 && xx < W_)
            v = wsb[yy * W_ + xx];
        sm[r][c] = v;
    }
    __syncthreads();

    // conv + sigmoid for the 56 positions (halo pre-zeroed, no bounds checks)
    if (tid < 56) {
        float acc = 0.0f;
        #pragma unroll
        for (int ky = 0; ky < 7; ++ky) {
            #pragma unroll
            for (int kx = 0; kx < 7; ++kx) {
                float2 am = sm[ky][tid + kx];
                acc = fmaf(am.x, sw[(ky * 7 + kx) * 2 + 0], acc);
                acc = fmaf(am.y, sw[(ky * 7 + kx) * 2 + 1], acc);
            }
        }
        satt[tid] = 1.0f / (1.0f + __expf(-acc));
    }
    __syncthreads();

    // multiply: 56 positions * 48 float4 = 2688 float4
    const size_t base4 = (size_t)rowg * (W_ * C4) + (size_t)x0 * C4;
    const nf4* xr   = (const nf4*)x + base4;
    nf4*       orow = (nf4*)out + base4;
    for (int f = tid; f < 56 * C4; f += 256) {
        nf4 v = xr[f];                              // regular load: L3 hit
        v = v * satt[f / C4];
        __builtin_nontemporal_store(v, &orow[f]);   // dead data: bypass caches
    }
}

extern "C" void kernel_launch(void* const* d_in, const int* in_sizes, int n_in,
                              void* d_out, int out_size, void* d_ws, size_t ws_size,
                              hipStream_t stream) {
    const float* x = (const float*)d_in[0];
    const float* w = (const float*)d_in[1];
    float* out = (float*)d_out;
    float2* ws2 = (float2*)d_ws;   // NPOS float2 = 3.2 MB

    for (int c = 0; c < NCHUNK; ++c) {
        // reduce chunk c: 100352/16 = 6272 blocks
        reduce_kernel<<<CPOS / 16, 256, 0, stream>>>(x, ws2, c * CPOS);
        // conv+mul chunk c: 2 blocks per row, 8*112 rows = 1792 blocks
        convmul_kernel<<<CHB * H_ * 2, 256, 0, stream>>>(x, ws2, w, out,
                                                         c * CHB * H_);
    }
}